// Round 5
// baseline (173.104 us; speedup 1.0000x reference)
//
#include <hip/hip_runtime.h>
#include <hip/hip_bf16.h>

// Fused 34->128->128->1 MLP with embedding lerp-gather, bf16 MFMA.
// R5 layout: block=256 thr=4 waves; wave nq owns ALL 64 rows x 32 hidden
// cols [nq*32, nq*32+32) per 64-point tile (column-quarter split).
// Rationale (R1-R4 counters): wave reg alloc is VGPR+AGPR quantized to 64;
// old row/col-half split needed 96 weight VGPRs -> total ~164 -> 192 alloc
// -> 2 waves/SIMD (19% occ, 110us). Col-quarter halves weights to 48 ->
// total ~115 -> 128 alloc -> 4 waves/SIMD, 4 blocks/CU resident.
// R2 keepers: bias in acc init, fmed3 clamp, packed bf16 cvt, H0S=132.
// R3 lesson: never let launch_bounds force spills (FETCH 9.5MB->1.28GB).
//            (256,4) budget=128 >= design ~115, OK; watch FETCH for spill.

using bf16x8 = __attribute__((ext_vector_type(8))) short;   // 8 bf16 = 4 VGPRs
using f32x4  = __attribute__((ext_vector_type(4))) float;   // MFMA C/D

#define NPTS    1000000
#define NUMEMB  6572
#define HID     128
#define M_IT    64          // points per block-iteration
#define A0S     72          // A0 row stride in bf16 (64 + 8 pad)
#define H0S     132         // H0 row stride in bf16 (128 + 4 pad)
#define TILES   (NPTS / M_IT)   // 15625 exactly
#define NBLOCKS 1024        // 4 blocks/CU resident on 256 CUs

__device__ __forceinline__ unsigned short bf16r(float f) {
    unsigned u;
    __builtin_memcpy(&u, &f, 4);
    u = (u + 0x7fffu + ((u >> 16) & 1u)) >> 16;
    return (unsigned short)u;
}
__device__ __forceinline__ unsigned pk2(float a, float b) {
    // packed RNE f32x2 -> bf16x2 (v_cvt_pk_bf16_f32 on gfx950)
    float2 f2; f2.x = a; f2.y = b;
    __hip_bfloat162 h = __float22bfloat162_rn(f2);
    unsigned u;
    __builtin_memcpy(&u, &h, 4);
    return u;
}
__device__ __forceinline__ float clamp01(float x) {
    return __builtin_amdgcn_fmed3f(x, 0.f, 1.f);
}

__global__ __launch_bounds__(256, 4)
void mlp_fused(const float* __restrict__ x,
               const float* __restrict__ emb,
               const float* __restrict__ em_table,
               const float* __restrict__ W0, const float* __restrict__ b0,
               const float* __restrict__ W1, const float* __restrict__ b1,
               const float* __restrict__ W2, const float* __restrict__ b2,
               float* __restrict__ out)
{
    __shared__ __align__(16) unsigned short A0[M_IT * A0S];  // bf16 bits
    __shared__ __align__(16) unsigned short H0[M_IT * H0S];  // bf16 bits
    __shared__ float PART[M_IT * 4];

    const int tid  = threadIdx.x;
    const int lane = tid & 63;
    const int nq   = tid >> 6;   // column quarter: cols [nq*32, nq*32+32)
    const int q    = lane >> 4;  // quad within wave
    const int cl   = lane & 15;

    // zero A0 once (cols 34..71 stay zero forever; build overwrites 0..33)
    for (int i = tid; i < M_IT * A0S; i += 256) A0[i] = 0;

    // ---- one-time: weight B-fragments into registers ----
    // Input dim order is [em(32), x(2), pad] => W0 logical row k maps to:
    //   k<32 -> W0 row 2+k ; k==32 -> row 0 ; k==33 -> row 1 ; k>=34 -> 0
    bf16x8 w0f[2][2];
    for (int kt = 0; kt < 2; ++kt)
        for (int j = 0; j < 2; ++j) {
            const int n = (nq * 2 + j) * 16 + cl;
            bf16x8 v;
            #pragma unroll
            for (int e = 0; e < 8; ++e) {
                const int k = kt * 32 + q * 8 + e;
                float val = 0.f;
                if (k < 32)       val = W0[(2 + k) * HID + n];
                else if (k == 32) val = W0[0 * HID + n];
                else if (k == 33) val = W0[1 * HID + n];
                v[e] = (short)bf16r(val);
            }
            w0f[kt][j] = v;
        }

    bf16x8 w1f[4][2];
    for (int kt = 0; kt < 4; ++kt)
        for (int j = 0; j < 2; ++j) {
            const int n = (nq * 2 + j) * 16 + cl;
            bf16x8 v;
            #pragma unroll
            for (int e = 0; e < 8; ++e) {
                const int k = kt * 32 + q * 8 + e;
                v[e] = (short)bf16r(W1[k * HID + n]);
            }
            w1f[kt][j] = v;
        }

    float b0f[2], b1f[2], w2f[2];
    for (int j = 0; j < 2; ++j) {
        const int n = (nq * 2 + j) * 16 + cl;
        b0f[j] = b0[n];
        b1f[j] = b1[n];
        w2f[j] = W2[n];
    }
    const float bias2 = b2[0];

    __syncthreads();   // A0 zeroing visible before first build

    for (int t = blockIdx.x; t < TILES; t += gridDim.x) {
        const int base = t * M_IT;

        // ---- stage inputs into A0 (4 threads per point) ----
        {
            const int p  = tid >> 2;
            const int s  = tid & 3;
            const int gp = base + p;
            const float fe = emb[gp];
            const int e1 = (int)fe;
            int e2 = e1 + 1; if (e2 > NUMEMB - 1) e2 = NUMEMB - 1;
            const float r = fe - (float)e1;
            const float4* p1 = (const float4*)(em_table + e1 * 32 + s * 8);
            const float4* p2 = (const float4*)(em_table + e2 * 32 + s * 8);
            const float4 a0v = p1[0], a1v = p1[1];
            const float4 c0v = p2[0], c1v = p2[1];
            uint4 d;
            d.x = pk2(a0v.x + (c0v.x - a0v.x) * r, a0v.y + (c0v.y - a0v.y) * r);
            d.y = pk2(a0v.z + (c0v.z - a0v.z) * r, a0v.w + (c0v.w - a0v.w) * r);
            d.z = pk2(a1v.x + (c1v.x - a1v.x) * r, a1v.y + (c1v.y - a1v.y) * r);
            d.w = pk2(a1v.z + (c1v.z - a1v.z) * r, a1v.w + (c1v.w - a1v.w) * r);
            *(uint4*)&A0[p * A0S + s * 8] = d;
            if (s == 0) {
                const float2 xv = *(const float2*)(x + 2 * gp);
                *(unsigned*)&A0[p * A0S + 32] = pk2(xv.x, xv.y);
            }
        }
        __syncthreads();

        // ---- layer 0: [64 x 64pad] @ [64 x 32] per wave (bias in acc) ----
        f32x4 acc[4][2];
        #pragma unroll
        for (int mt = 0; mt < 4; ++mt)
            #pragma unroll
            for (int j = 0; j < 2; ++j)
                acc[mt][j] = (f32x4){b0f[j], b0f[j], b0f[j], b0f[j]};
        #pragma unroll
        for (int mt = 0; mt < 4; ++mt) {
            const int row = mt * 16 + cl;
            #pragma unroll
            for (int kt = 0; kt < 2; ++kt) {
                bf16x8 a = *(const bf16x8*)&A0[row * A0S + kt * 32 + q * 8];
                #pragma unroll
                for (int j = 0; j < 2; ++j)
                    acc[mt][j] = __builtin_amdgcn_mfma_f32_16x16x32_bf16(
                        a, w0f[kt][j], acc[mt][j], 0, 0, 0);
            }
        }
        // epilogue: clip01 + packed cvt -> H0 (C-layout scatter)
        #pragma unroll
        for (int mt = 0; mt < 4; ++mt)
            #pragma unroll
            for (int j = 0; j < 2; ++j) {
                const int col = (nq * 2 + j) * 16 + cl;
                const int row = mt * 16 + q * 4;
                const f32x4 v = acc[mt][j];
                const unsigned d01 = pk2(clamp01(v[0]), clamp01(v[1]));
                const unsigned d23 = pk2(clamp01(v[2]), clamp01(v[3]));
                H0[(row + 0) * H0S + col] = (unsigned short)d01;
                H0[(row + 1) * H0S + col] = (unsigned short)(d01 >> 16);
                H0[(row + 2) * H0S + col] = (unsigned short)d23;
                H0[(row + 3) * H0S + col] = (unsigned short)(d23 >> 16);
            }
        __syncthreads();

        // ---- layer 1: [64 x 128] @ [128 x 32] per wave (bias in acc) ----
        #pragma unroll
        for (int mt = 0; mt < 4; ++mt)
            #pragma unroll
            for (int j = 0; j < 2; ++j)
                acc[mt][j] = (f32x4){b1f[j], b1f[j], b1f[j], b1f[j]};
        #pragma unroll
        for (int mt = 0; mt < 4; ++mt) {
            const int row = mt * 16 + cl;
            #pragma unroll
            for (int kt = 0; kt < 4; ++kt) {
                bf16x8 a = *(const bf16x8*)&H0[row * H0S + kt * 32 + q * 8];
                #pragma unroll
                for (int j = 0; j < 2; ++j)
                    acc[mt][j] = __builtin_amdgcn_mfma_f32_16x16x32_bf16(
                        a, w1f[kt][j], acc[mt][j], 0, 0, 0);
            }
        }

        // ---- layer 1 epilogue + layer 2 dot (fp32 VALU) ----
        #pragma unroll
        for (int mt = 0; mt < 4; ++mt) {
            float sr0 = 0.f, sr1 = 0.f, sr2 = 0.f, sr3 = 0.f;
            #pragma unroll
            for (int j = 0; j < 2; ++j) {
                const f32x4 v = acc[mt][j];
                sr0 += clamp01(v[0]) * w2f[j];
                sr1 += clamp01(v[1]) * w2f[j];
                sr2 += clamp01(v[2]) * w2f[j];
                sr3 += clamp01(v[3]) * w2f[j];
            }
            // reduce over the 16 lanes sharing q (cols); stays within quad
            #pragma unroll
            for (int msk = 1; msk < 16; msk <<= 1) {
                sr0 += __shfl_xor(sr0, msk);
                sr1 += __shfl_xor(sr1, msk);
                sr2 += __shfl_xor(sr2, msk);
                sr3 += __shfl_xor(sr3, msk);
            }
            if (cl == 0) {
                const int rbase = mt * 16 + q * 4;
                PART[(rbase + 0) * 4 + nq] = sr0;
                PART[(rbase + 1) * 4 + nq] = sr1;
                PART[(rbase + 2) * 4 + nq] = sr2;
                PART[(rbase + 3) * 4 + nq] = sr3;
            }
        }
        __syncthreads();

        if (tid < 64) {
            const float z = PART[tid * 4 + 0] + PART[tid * 4 + 1]
                          + PART[tid * 4 + 2] + PART[tid * 4 + 3] + bias2;
            out[base + tid] = 1.f / (1.f + __expf(-z));
        }
        // no trailing sync needed: PART is rewritten only after two more
        // barriers; A0 build writes only cols 0..33 (disjoint from reads)
    }
}

extern "C" void kernel_launch(void* const* d_in, const int* in_sizes, int n_in,
                              void* d_out, int out_size, void* d_ws, size_t ws_size,
                              hipStream_t stream) {
    const float* x   = (const float*)d_in[0];
    const float* emb = (const float*)d_in[1];
    const float* emt = (const float*)d_in[2];
    const float* W0  = (const float*)d_in[3];
    const float* b0  = (const float*)d_in[4];
    const float* W1  = (const float*)d_in[5];
    const float* b1  = (const float*)d_in[6];
    const float* W2  = (const float*)d_in[7];
    const float* b2  = (const float*)d_in[8];
    mlp_fused<<<NBLOCKS, 256, 0, stream>>>(x, emb, emt, W0, b0, W1, b1, W2, b2,
                                           (float*)d_out);
}

// Round 6
// 140.498 us; speedup vs baseline: 1.2321x; 1.2321x over previous
//
#include <hip/hip_runtime.h>
#include <hip/hip_bf16.h>

// Fused 34->128->128->1 MLP with embedding lerp-gather, bf16 MFMA.
// R5 layout kept: block=256 thr=4 waves; wave nq owns ALL 64 rows x 32 hidden
// cols [nq*32,+32) per 64-point tile (col-quarter split, register-light:
// VGPR=64, 4 waves/SIMD resident).
// R6: kernel is LDS-PIPE ISSUE BOUND (R5 counters: occupancy 19->35% with
// zero speedup; per-tile LDS instrs ~560 x ~7cyc ~= measured 4520 cyc/tile).
// __shfl_xor is ds_bpermute on CDNA => moved 16-lane reduction to DPP
// (v_add_f32 row_shr:1/2/4/8, VALU pipe), and PART scalar writes -> one
// ds_write_b128/mt from lane cl==15. LDS instrs 560 -> ~244 per tile.
// R2 keepers: bias in acc init, fmed3 clamp, packed bf16 cvt, H0S=132.
// R3 lesson: (256,4) budget 128 regs >= design ~100; watch FETCH for spill.

using bf16x8 = __attribute__((ext_vector_type(8))) short;   // 8 bf16 = 4 VGPRs
using f32x4  = __attribute__((ext_vector_type(4))) float;   // MFMA C/D

#define NPTS    1000000
#define NUMEMB  6572
#define HID     128
#define M_IT    64          // points per block-iteration
#define A0S     72          // A0 row stride in bf16 (64 + 8 pad)
#define H0S     132         // H0 row stride in bf16 (128 + 4 pad)
#define TILES   (NPTS / M_IT)   // 15625 exactly
#define NBLOCKS 1024        // 4 blocks/CU resident on 256 CUs

__device__ __forceinline__ unsigned short bf16r(float f) {
    unsigned u;
    __builtin_memcpy(&u, &f, 4);
    u = (u + 0x7fffu + ((u >> 16) & 1u)) >> 16;
    return (unsigned short)u;
}
__device__ __forceinline__ unsigned pk2(float a, float b) {
    // packed RNE f32x2 -> bf16x2 (v_cvt_pk_bf16_f32 on gfx950)
    float2 f2; f2.x = a; f2.y = b;
    __hip_bfloat162 h = __float22bfloat162_rn(f2);
    unsigned u;
    __builtin_memcpy(&u, &h, 4);
    return u;
}
__device__ __forceinline__ float clamp01(float x) {
    return __builtin_amdgcn_fmed3f(x, 0.f, 1.f);
}

// Sum across each DPP row (16 contiguous lanes) on the VALU pipe.
// After row_shr 1,2,4,8 the full 16-lane sum lands in lane (cl==15) of
// each row. bound_ctrl=true -> out-of-row source reads 0.
__device__ __forceinline__ float dpp_row_sum16(float x) {
    int xi;
    __builtin_memcpy(&xi, &x, 4);
    {   int t = __builtin_amdgcn_update_dpp(0, xi, 0x111, 0xf, 0xf, true);
        float tf; __builtin_memcpy(&tf, &t, 4); x += tf;
        __builtin_memcpy(&xi, &x, 4); }
    {   int t = __builtin_amdgcn_update_dpp(0, xi, 0x112, 0xf, 0xf, true);
        float tf; __builtin_memcpy(&tf, &t, 4); x += tf;
        __builtin_memcpy(&xi, &x, 4); }
    {   int t = __builtin_amdgcn_update_dpp(0, xi, 0x114, 0xf, 0xf, true);
        float tf; __builtin_memcpy(&tf, &t, 4); x += tf;
        __builtin_memcpy(&xi, &x, 4); }
    {   int t = __builtin_amdgcn_update_dpp(0, xi, 0x118, 0xf, 0xf, true);
        float tf; __builtin_memcpy(&tf, &t, 4); x += tf; }
    return x;
}

__global__ __launch_bounds__(256, 4)
void mlp_fused(const float* __restrict__ x,
               const float* __restrict__ emb,
               const float* __restrict__ em_table,
               const float* __restrict__ W0, const float* __restrict__ b0,
               const float* __restrict__ W1, const float* __restrict__ b1,
               const float* __restrict__ W2, const float* __restrict__ b2,
               float* __restrict__ out)
{
    __shared__ __align__(16) unsigned short A0[M_IT * A0S];  // bf16 bits
    __shared__ __align__(16) unsigned short H0[M_IT * H0S];  // bf16 bits
    __shared__ __align__(16) float PART[4][M_IT];            // [nq][row]

    const int tid  = threadIdx.x;
    const int lane = tid & 63;
    const int nq   = tid >> 6;   // column quarter: cols [nq*32, nq*32+32)
    const int q    = lane >> 4;  // quad within wave
    const int cl   = lane & 15;

    // zero A0 once (cols 34..71 stay zero forever; build overwrites 0..33)
    for (int i = tid; i < M_IT * A0S; i += 256) A0[i] = 0;

    // ---- one-time: weight B-fragments into registers ----
    // Input dim order is [em(32), x(2), pad] => W0 logical row k maps to:
    //   k<32 -> W0 row 2+k ; k==32 -> row 0 ; k==33 -> row 1 ; k>=34 -> 0
    bf16x8 w0f[2][2];
    for (int kt = 0; kt < 2; ++kt)
        for (int j = 0; j < 2; ++j) {
            const int n = (nq * 2 + j) * 16 + cl;
            bf16x8 v;
            #pragma unroll
            for (int e = 0; e < 8; ++e) {
                const int k = kt * 32 + q * 8 + e;
                float val = 0.f;
                if (k < 32)       val = W0[(2 + k) * HID + n];
                else if (k == 32) val = W0[0 * HID + n];
                else if (k == 33) val = W0[1 * HID + n];
                v[e] = (short)bf16r(val);
            }
            w0f[kt][j] = v;
        }

    bf16x8 w1f[4][2];
    for (int kt = 0; kt < 4; ++kt)
        for (int j = 0; j < 2; ++j) {
            const int n = (nq * 2 + j) * 16 + cl;
            bf16x8 v;
            #pragma unroll
            for (int e = 0; e < 8; ++e) {
                const int k = kt * 32 + q * 8 + e;
                v[e] = (short)bf16r(W1[k * HID + n]);
            }
            w1f[kt][j] = v;
        }

    float b0f[2], b1f[2], w2f[2];
    for (int j = 0; j < 2; ++j) {
        const int n = (nq * 2 + j) * 16 + cl;
        b0f[j] = b0[n];
        b1f[j] = b1[n];
        w2f[j] = W2[n];
    }
    const float bias2 = b2[0];

    __syncthreads();   // A0 zeroing visible before first build

    for (int t = blockIdx.x; t < TILES; t += gridDim.x) {
        const int base = t * M_IT;

        // ---- stage inputs into A0 (4 threads per point) ----
        {
            const int p  = tid >> 2;
            const int s  = tid & 3;
            const int gp = base + p;
            const float fe = emb[gp];
            const int e1 = (int)fe;
            int e2 = e1 + 1; if (e2 > NUMEMB - 1) e2 = NUMEMB - 1;
            const float r = fe - (float)e1;
            const float4* p1 = (const float4*)(em_table + e1 * 32 + s * 8);
            const float4* p2 = (const float4*)(em_table + e2 * 32 + s * 8);
            const float4 a0v = p1[0], a1v = p1[1];
            const float4 c0v = p2[0], c1v = p2[1];
            uint4 d;
            d.x = pk2(a0v.x + (c0v.x - a0v.x) * r, a0v.y + (c0v.y - a0v.y) * r);
            d.y = pk2(a0v.z + (c0v.z - a0v.z) * r, a0v.w + (c0v.w - a0v.w) * r);
            d.z = pk2(a1v.x + (c1v.x - a1v.x) * r, a1v.y + (c1v.y - a1v.y) * r);
            d.w = pk2(a1v.z + (c1v.z - a1v.z) * r, a1v.w + (c1v.w - a1v.w) * r);
            *(uint4*)&A0[p * A0S + s * 8] = d;
            if (s == 0) {
                const float2 xv = *(const float2*)(x + 2 * gp);
                *(unsigned*)&A0[p * A0S + 32] = pk2(xv.x, xv.y);
            }
        }
        __syncthreads();

        // ---- layer 0: [64 x 64pad] @ [64 x 32] per wave (bias in acc) ----
        f32x4 acc[4][2];
        #pragma unroll
        for (int mt = 0; mt < 4; ++mt)
            #pragma unroll
            for (int j = 0; j < 2; ++j)
                acc[mt][j] = (f32x4){b0f[j], b0f[j], b0f[j], b0f[j]};
        #pragma unroll
        for (int mt = 0; mt < 4; ++mt) {
            const int row = mt * 16 + cl;
            #pragma unroll
            for (int kt = 0; kt < 2; ++kt) {
                bf16x8 a = *(const bf16x8*)&A0[row * A0S + kt * 32 + q * 8];
                #pragma unroll
                for (int j = 0; j < 2; ++j)
                    acc[mt][j] = __builtin_amdgcn_mfma_f32_16x16x32_bf16(
                        a, w0f[kt][j], acc[mt][j], 0, 0, 0);
            }
        }
        // epilogue: clip01 + packed cvt -> H0 (C-layout scatter)
        #pragma unroll
        for (int mt = 0; mt < 4; ++mt)
            #pragma unroll
            for (int j = 0; j < 2; ++j) {
                const int col = (nq * 2 + j) * 16 + cl;
                const int row = mt * 16 + q * 4;
                const f32x4 v = acc[mt][j];
                const unsigned d01 = pk2(clamp01(v[0]), clamp01(v[1]));
                const unsigned d23 = pk2(clamp01(v[2]), clamp01(v[3]));
                H0[(row + 0) * H0S + col] = (unsigned short)d01;
                H0[(row + 1) * H0S + col] = (unsigned short)(d01 >> 16);
                H0[(row + 2) * H0S + col] = (unsigned short)d23;
                H0[(row + 3) * H0S + col] = (unsigned short)(d23 >> 16);
            }
        __syncthreads();

        // ---- layer 1: [64 x 128] @ [128 x 32] per wave (bias in acc) ----
        #pragma unroll
        for (int mt = 0; mt < 4; ++mt)
            #pragma unroll
            for (int j = 0; j < 2; ++j)
                acc[mt][j] = (f32x4){b1f[j], b1f[j], b1f[j], b1f[j]};
        #pragma unroll
        for (int mt = 0; mt < 4; ++mt) {
            const int row = mt * 16 + cl;
            #pragma unroll
            for (int kt = 0; kt < 4; ++kt) {
                bf16x8 a = *(const bf16x8*)&H0[row * H0S + kt * 32 + q * 8];
                #pragma unroll
                for (int j = 0; j < 2; ++j)
                    acc[mt][j] = __builtin_amdgcn_mfma_f32_16x16x32_bf16(
                        a, w1f[kt][j], acc[mt][j], 0, 0, 0);
            }
        }

        // ---- layer 1 epilogue + layer 2 dot: VALU fma + DPP row-reduce ----
        #pragma unroll
        for (int mt = 0; mt < 4; ++mt) {
            float sr0 = 0.f, sr1 = 0.f, sr2 = 0.f, sr3 = 0.f;
            #pragma unroll
            for (int j = 0; j < 2; ++j) {
                const f32x4 v = acc[mt][j];
                sr0 += clamp01(v[0]) * w2f[j];
                sr1 += clamp01(v[1]) * w2f[j];
                sr2 += clamp01(v[2]) * w2f[j];
                sr3 += clamp01(v[3]) * w2f[j];
            }
            // 16-lane column sums on the VALU pipe (no ds_bpermute)
            sr0 = dpp_row_sum16(sr0);
            sr1 = dpp_row_sum16(sr1);
            sr2 = dpp_row_sum16(sr2);
            sr3 = dpp_row_sum16(sr3);
            if (cl == 15) {
                // rows mt*16 + q*4 .. +3, one vector store per mt
                f32x4 v4 = (f32x4){sr0, sr1, sr2, sr3};
                *(f32x4*)&PART[nq][mt * 16 + q * 4] = v4;
            }
        }
        __syncthreads();

        if (tid < 64) {
            const float z = PART[0][tid] + PART[1][tid]
                          + PART[2][tid] + PART[3][tid] + bias2;
            out[base + tid] = 1.f / (1.f + __expf(-z));
        }
        // no trailing sync needed: PART is rewritten only after two more
        // barriers; A0 build writes only cols 0..33 (disjoint from reads)
    }
}

extern "C" void kernel_launch(void* const* d_in, const int* in_sizes, int n_in,
                              void* d_out, int out_size, void* d_ws, size_t ws_size,
                              hipStream_t stream) {
    const float* x   = (const float*)d_in[0];
    const float* emb = (const float*)d_in[1];
    const float* emt = (const float*)d_in[2];
    const float* W0  = (const float*)d_in[3];
    const float* b0  = (const float*)d_in[4];
    const float* W1  = (const float*)d_in[5];
    const float* b1  = (const float*)d_in[6];
    const float* W2  = (const float*)d_in[7];
    const float* b2  = (const float*)d_in[8];
    mlp_fused<<<NBLOCKS, 256, 0, stream>>>(x, emb, emt, W0, b0, W1, b1, W2, b2,
                                           (float*)d_out);
}

// Round 7
// 133.174 us; speedup vs baseline: 1.2998x; 1.0550x over previous
//
#include <hip/hip_runtime.h>
#include <hip/hip_bf16.h>

// Fused 34->128->128->1 MLP with embedding lerp-gather, bf16 MFMA.
// R7: TRANSPOSED GEMMs. D = W^T @ X^T : A-operand = weight frags (static,
// in VGPRs), B-operand = activations with lane = point. Wave nq owns hidden
// [nq*32,+32) as the MFMA m-dim; points are the n-dim (4 blocks of 16).
//   - epi0: lane holds 4 CONSECUTIVE hidden per point -> ds_write_b64
//     (32/tile) instead of 128 ds_write_b16 scatters.
//   - layer2 dot is within-lane (8 fma) -> the 256 DPP adds/tile gone.
//   - H0S=136: row stride 272B % 16 == 0 -> b128 reads stay single-op
//     (132's 264B stride forced ds_read2_b64 splits); banks 68 dwords
//     % 32 = 4 -> 2-way on reads (free per m136).
// Evidence trail: R5 (occ 19->35%, no speedup) + R6 (removing 256
// ds_bpermute/tile: 115->80us) => kernel is LDS-pipe issue-bound; this
// round cuts LDS ops/tile 252 -> ~168.
// R3 lesson: launch_bounds must not squeeze below liveness (~135 regs here)
// -> (256,3) budget ~170, grid 768 = 3 blocks/CU. FETCH ~9.5MB == no spill.

using bf16x8 = __attribute__((ext_vector_type(8))) short;   // 8 bf16 = 4 VGPRs
using f32x4  = __attribute__((ext_vector_type(4))) float;   // MFMA C/D

#define NPTS    1000000
#define NUMEMB  6572
#define HID     128
#define M_IT    64          // points per block-iteration
#define A0S     72          // A0 row stride in bf16 (144B, 16B-aligned rows)
#define H0S     136         // H0 row stride in bf16 (272B, 16B-aligned rows)
#define TILES   (NPTS / M_IT)   // 15625 exactly
#define NBLOCKS 768         // 3 blocks/CU on 256 CUs

__device__ __forceinline__ unsigned short bf16r(float f) {
    unsigned u;
    __builtin_memcpy(&u, &f, 4);
    u = (u + 0x7fffu + ((u >> 16) & 1u)) >> 16;
    return (unsigned short)u;
}
__device__ __forceinline__ unsigned pk2(float a, float b) {
    // packed RNE f32x2 -> bf16x2 (v_cvt_pk_bf16_f32 on gfx950)
    float2 f2; f2.x = a; f2.y = b;
    __hip_bfloat162 h = __float22bfloat162_rn(f2);
    unsigned u;
    __builtin_memcpy(&u, &h, 4);
    return u;
}
__device__ __forceinline__ float clamp01(float x) {
    return __builtin_amdgcn_fmed3f(x, 0.f, 1.f);
}

__global__ __launch_bounds__(256, 3)
void mlp_fused(const float* __restrict__ x,
               const float* __restrict__ emb,
               const float* __restrict__ em_table,
               const float* __restrict__ W0, const float* __restrict__ b0,
               const float* __restrict__ W1, const float* __restrict__ b1,
               const float* __restrict__ W2, const float* __restrict__ b2,
               float* __restrict__ out)
{
    __shared__ __align__(16) unsigned short A0[M_IT * A0S];  // bf16 [pt][in]
    __shared__ __align__(16) unsigned short H0[M_IT * H0S];  // bf16 [pt][hid]
    __shared__ __align__(16) float PART[16][M_IT];           // [nq*4+q][pt]

    const int tid  = threadIdx.x;
    const int lane = tid & 63;
    const int nq   = tid >> 6;   // wave's hidden block: [nq*32, nq*32+32)
    const int q    = lane >> 4;  // quad within wave
    const int cl   = lane & 15;

    // zero A0 once (cols 34..71 stay zero forever; build overwrites 0..33)
    for (int i = tid; i < M_IT * A0S; i += 256) A0[i] = 0;

    // ---- one-time: weight A-fragments (W^T) into registers ----
    // A-frag for mfma_16x16x32: lane holds A[m = cl][k = q*8+e].
    // m = hidden col of W, k = input dim. Input order [em(32), x(2), pad]:
    //   k<32 -> W0 row 2+k ; k==32 -> row 0 ; k==33 -> row 1 ; k>=34 -> 0
    bf16x8 w0t[2][2];   // [hb][kt]
    for (int hb = 0; hb < 2; ++hb)
        for (int kt = 0; kt < 2; ++kt) {
            const int col = nq * 32 + hb * 16 + cl;
            bf16x8 v;
            #pragma unroll
            for (int e = 0; e < 8; ++e) {
                const int k = kt * 32 + q * 8 + e;
                float val = 0.f;
                if (k < 32)       val = W0[(2 + k) * HID + col];
                else if (k == 32) val = W0[0 * HID + col];
                else if (k == 33) val = W0[1 * HID + col];
                v[e] = (short)bf16r(val);
            }
            w0t[hb][kt] = v;
        }

    bf16x8 w1t[2][4];   // [hb][kt]: A[m=h2][k=h1] = W1[h1*HID + h2]
    for (int hb = 0; hb < 2; ++hb)
        for (int kt = 0; kt < 4; ++kt) {
            const int col = nq * 32 + hb * 16 + cl;
            bf16x8 v;
            #pragma unroll
            for (int e = 0; e < 8; ++e) {
                const int k = kt * 32 + q * 8 + e;
                v[e] = (short)bf16r(W1[k * HID + col]);
            }
            w1t[hb][kt] = v;
        }

    // biases / W2, indexed by the C/D reg layout: h = nq*32+hb*16+q*4+r
    f32x4 b0q[2], b1q[2], w2q[2];
    for (int hb = 0; hb < 2; ++hb)
        for (int r = 0; r < 4; ++r) {
            const int h = nq * 32 + hb * 16 + q * 4 + r;
            b0q[hb][r] = b0[h];
            b1q[hb][r] = b1[h];
            w2q[hb][r] = W2[h];
        }
    const float bias2 = b2[0];

    __syncthreads();   // A0 zeroing visible before first build

    for (int t = blockIdx.x; t < TILES; t += gridDim.x) {
        const int base = t * M_IT;

        // ---- stage inputs into A0 (4 threads per point) ----
        {
            const int p  = tid >> 2;
            const int s  = tid & 3;
            const int gp = base + p;
            const float fe = emb[gp];
            const int e1 = (int)fe;
            int e2 = e1 + 1; if (e2 > NUMEMB - 1) e2 = NUMEMB - 1;
            const float r = fe - (float)e1;
            const float4* p1 = (const float4*)(em_table + e1 * 32 + s * 8);
            const float4* p2 = (const float4*)(em_table + e2 * 32 + s * 8);
            const float4 a0v = p1[0], a1v = p1[1];
            const float4 c0v = p2[0], c1v = p2[1];
            uint4 d;
            d.x = pk2(a0v.x + (c0v.x - a0v.x) * r, a0v.y + (c0v.y - a0v.y) * r);
            d.y = pk2(a0v.z + (c0v.z - a0v.z) * r, a0v.w + (c0v.w - a0v.w) * r);
            d.z = pk2(a1v.x + (c1v.x - a1v.x) * r, a1v.y + (c1v.y - a1v.y) * r);
            d.w = pk2(a1v.z + (c1v.z - a1v.z) * r, a1v.w + (c1v.w - a1v.w) * r);
            *(uint4*)&A0[p * A0S + s * 8] = d;
            if (s == 0) {
                const float2 xv = *(const float2*)(x + 2 * gp);
                *(unsigned*)&A0[p * A0S + 32] = pk2(xv.x, xv.y);
            }
        }
        __syncthreads();

        // ---- layer 0 (transposed): D[h][p] = W0^T @ X^T, bias in acc ----
        f32x4 acc[4][2];   // [pb][hb]
        #pragma unroll
        for (int pb = 0; pb < 4; ++pb)
            #pragma unroll
            for (int hb = 0; hb < 2; ++hb)
                acc[pb][hb] = b0q[hb];
        #pragma unroll
        for (int pb = 0; pb < 4; ++pb) {
            #pragma unroll
            for (int kt = 0; kt < 2; ++kt) {
                bf16x8 bfrag = *(const bf16x8*)
                    &A0[(pb * 16 + cl) * A0S + kt * 32 + q * 8];
                #pragma unroll
                for (int hb = 0; hb < 2; ++hb)
                    acc[pb][hb] = __builtin_amdgcn_mfma_f32_16x16x32_bf16(
                        w0t[hb][kt], bfrag, acc[pb][hb], 0, 0, 0);
            }
        }
        // epi0: lane = point, regs = 4 consecutive hidden -> one b64 store
        #pragma unroll
        for (int pb = 0; pb < 4; ++pb)
            #pragma unroll
            for (int hb = 0; hb < 2; ++hb) {
                const f32x4 v = acc[pb][hb];
                uint2 dd;
                dd.x = pk2(clamp01(v[0]), clamp01(v[1]));
                dd.y = pk2(clamp01(v[2]), clamp01(v[3]));
                *(uint2*)&H0[(pb * 16 + cl) * H0S
                             + nq * 32 + hb * 16 + q * 4] = dd;
            }
        __syncthreads();

        // ---- layer 1 (transposed): D[h2][p] = W1^T @ H0^T ----
        #pragma unroll
        for (int pb = 0; pb < 4; ++pb)
            #pragma unroll
            for (int hb = 0; hb < 2; ++hb)
                acc[pb][hb] = b1q[hb];
        #pragma unroll
        for (int pb = 0; pb < 4; ++pb) {
            #pragma unroll
            for (int kt = 0; kt < 4; ++kt) {
                bf16x8 bfrag = *(const bf16x8*)
                    &H0[(pb * 16 + cl) * H0S + kt * 32 + q * 8];
                #pragma unroll
                for (int hb = 0; hb < 2; ++hb)
                    acc[pb][hb] = __builtin_amdgcn_mfma_f32_16x16x32_bf16(
                        w1t[hb][kt], bfrag, acc[pb][hb], 0, 0, 0);
            }
        }

        // ---- epi1 + layer 2: within-lane dot over this lane's 8 h2 ----
        #pragma unroll
        for (int pb = 0; pb < 4; ++pb) {
            float s = 0.f;
            #pragma unroll
            for (int hb = 0; hb < 2; ++hb) {
                const f32x4 v = acc[pb][hb];
                s += clamp01(v[0]) * w2q[hb][0];
                s += clamp01(v[1]) * w2q[hb][1];
                s += clamp01(v[2]) * w2q[hb][2];
                s += clamp01(v[3]) * w2q[hb][3];
            }
            PART[nq * 4 + q][pb * 16 + cl] = s;
        }
        __syncthreads();

        if (tid < 64) {
            float z = bias2;
            #pragma unroll
            for (int i = 0; i < 16; ++i) z += PART[i][tid];
            out[base + tid] = 1.f / (1.f + __expf(-z));
        }
        // PART read -> next PART write separated by 2 barriers (staging sync
        // + epi0 sync); A0 build writes only cols 0..33 (disjoint from zeros)
    }
}

extern "C" void kernel_launch(void* const* d_in, const int* in_sizes, int n_in,
                              void* d_out, int out_size, void* d_ws, size_t ws_size,
                              hipStream_t stream) {
    const float* x   = (const float*)d_in[0];
    const float* emb = (const float*)d_in[1];
    const float* emt = (const float*)d_in[2];
    const float* W0  = (const float*)d_in[3];
    const float* b0  = (const float*)d_in[4];
    const float* W1  = (const float*)d_in[5];
    const float* b1  = (const float*)d_in[6];
    const float* W2  = (const float*)d_in[7];
    const float* b2  = (const float*)d_in[8];
    mlp_fused<<<NBLOCKS, 256, 0, stream>>>(x, emb, emt, W0, b0, W1, b1, W2, b2,
                                           (float*)d_out);
}